// Round 6
// baseline (493.554 us; speedup 1.0000x reference)
//
#include <hip/hip_runtime.h>

// SelfAttnMatch: B=32, L=1024, D=1024, fp32 in/out.
//   scores = x @ x^T (diag zeroed); t = scores*mask; a = softmax(t)*mask;
//   alpha = a / (sum(a)+1e-13); out = alpha @ x
//
// R8:
//   - REVERT R7's Vs permutation (it fixed write-phase conflicts but
//     introduced 2-way read conflicts on the row-pair split: 1.99e7 ->
//     2.83e7, 129 -> 157us). pv LDS layout back to R6 exactly.
//   - DELETE sam_cvt (~35us + 192MB HBM): both MFMA kernels stage from
//     fp32 x with inline conversion (proven R1-fallback patterns:
//     cvt8 staging in scores, float2-pair transpose in pv).
//   - ws gate drops to 64MB (alpha only).
// Provenance: R6 = XCD-bijective swizzle both kernels (FETCH 262->~90MB).
//   Failed experiments deleted: scores4 reg-pipeline (R5), pv3/xhT (R4),
//   Vs permutation (R7) — see session journal.
// Fallback path (small ws): R1 kernels verbatim.

typedef _Float16 half8 __attribute__((ext_vector_type(8)));
typedef float f32x4 __attribute__((ext_vector_type(4)));

#define L_ 1024
#define D_ 1024

__device__ __forceinline__ half8 cvt8(const float* src) {
  float4 a = *(const float4*)src;
  float4 c = *(const float4*)(src + 4);
  half8 h;
  h[0] = (_Float16)a.x; h[1] = (_Float16)a.y; h[2] = (_Float16)a.z; h[3] = (_Float16)a.w;
  h[4] = (_Float16)c.x; h[5] = (_Float16)c.y; h[6] = (_Float16)c.z; h[7] = (_Float16)c.w;
  return h;
}

// ===========================================================================
// FAST PATH
// ===========================================================================

// ---------------------------------------------------------------------------
// phase1: full-row scores + softmax -> normalized alpha fp16 (ws).
// grid (16, 32); 1024 threads = 16 waves in a 2x8 (qw,kw) grid.
// Block tile 64q x 1024k; stages fp32 x with inline cvt (R1-proven pattern).
// XCD-bijective swizzle: XCD c gets wid [64c,64c+64) = 4 whole b's.
// ---------------------------------------------------------------------------
__global__ __launch_bounds__(1024, 4) void sam_scores5(
    const float* __restrict__ x, const int* __restrict__ xmask,
    _Float16* __restrict__ alpha)
{
  const int id   = blockIdx.y * 16 + blockIdx.x;   // 512 blocks
  const int wid  = (id & 7) * 64 + (id >> 3);      // bijective XCD chunking
  const int qblk = wid & 15;
  const int b    = wid >> 4;
  const int tid  = threadIdx.x;
  const int wave = tid >> 6;
  const int lane = tid & 63;
  const int qw   = wave >> 3;        // 0..1 -> 32 q rows
  const int kw   = wave & 7;         // 0..7 -> 128 k cols
  const int l15  = lane & 15;
  const int quad = lane >> 4;

  __shared__ _Float16 Qs[64][72];    // 9 KB (stride 72 = conflict-free b128)
  __shared__ union KsAt {
    _Float16 Ks[1024][72];           // 144 KB staging view
    _Float16 At[64][1032];           // 132 KB alpha-transpose view (epilogue)
  } KU;
  __shared__ float rmax[8][64];      // 2 KB
  __shared__ float rsum[8][64];      // 2 KB

  const float* xb = x + (size_t)b * L_ * D_;
  const int srow = tid >> 3;             // staging row (8 thr/row)
  const int scol = (tid & 7) * 8;        // 8-elem chunk (32 B fp32)

  f32x4 acc[2][8];
#pragma unroll
  for (int m = 0; m < 2; ++m)
#pragma unroll
    for (int n = 0; n < 8; ++n)
#pragma unroll
      for (int r = 0; r < 4; ++r) acc[m][n][r] = 0.0f;

  for (int dc = 0; dc < 16; ++dc) {      // D in chunks of 64
    if (tid < 512)
      *(half8*)&Qs[srow][scol] =
          cvt8(xb + (size_t)(qblk * 64 + srow) * D_ + dc * 64 + scol);
#pragma unroll
    for (int i = 0; i < 8; ++i)
      *(half8*)&KU.Ks[srow + 128 * i][scol] =
          cvt8(xb + (size_t)(srow + 128 * i) * D_ + dc * 64 + scol);
    __syncthreads();
#pragma unroll
    for (int ks = 0; ks < 2; ++ks) {
      half8 af[2], bf[8];
#pragma unroll
      for (int m = 0; m < 2; ++m)
        af[m] = *(half8*)&Qs[qw * 32 + 16 * m + l15][ks * 32 + quad * 8];
#pragma unroll
      for (int n = 0; n < 8; ++n)
        bf[n] = *(half8*)&KU.Ks[kw * 128 + 16 * n + l15][ks * 32 + quad * 8];
#pragma unroll
      for (int m = 0; m < 2; ++m)
#pragma unroll
        for (int n = 0; n < 8; ++n)
          acc[m][n] = __builtin_amdgcn_mfma_f32_16x16x32_f16(af[m], bf[n], acc[m][n], 0, 0, 0);
    }
    __syncthreads();
  }

  // ---- epilogue: diag zero, mask, full-row softmax, normalized store ----
  float mkv[8];
#pragma unroll
  for (int n = 0; n < 8; ++n)
    mkv[n] = (float)xmask[b * L_ + kw * 128 + 16 * n + l15];

  float rst[2][4];
#pragma unroll
  for (int m = 0; m < 2; ++m)
#pragma unroll
    for (int r = 0; r < 4; ++r) rst[m][r] = 0.0f;

#pragma unroll
  for (int m = 0; m < 2; ++m)
#pragma unroll
    for (int r = 0; r < 4; ++r) {
      const int gq = qblk * 64 + qw * 32 + 16 * m + quad * 4 + r;
#pragma unroll
      for (int n = 0; n < 8; ++n) {
        const int gk = kw * 128 + 16 * n + l15;
        float v = acc[m][n][r];
        if (gq == gk) v = 0.0f;
        v = (mkv[n] != 0.0f) ? v : 0.0f;
        acc[m][n][r] = v;
        rst[m][r] = fmaxf(rst[m][r], v);
      }
    }
#pragma unroll
  for (int m = 0; m < 2; ++m)
#pragma unroll
    for (int r = 0; r < 4; ++r) {
      float v = rst[m][r];
      v = fmaxf(v, __shfl_xor(v, 1));
      v = fmaxf(v, __shfl_xor(v, 2));
      v = fmaxf(v, __shfl_xor(v, 4));
      v = fmaxf(v, __shfl_xor(v, 8));
      rst[m][r] = v;
    }
  if (l15 == 0) {
#pragma unroll
    for (int m = 0; m < 2; ++m)
#pragma unroll
      for (int r = 0; r < 4; ++r)
        rmax[kw][qw * 32 + 16 * m + quad * 4 + r] = rst[m][r];
  }
  __syncthreads();

  float Mrow[2][4];
#pragma unroll
  for (int m = 0; m < 2; ++m)
#pragma unroll
    for (int r = 0; r < 4; ++r) {
      const int row = qw * 32 + 16 * m + quad * 4 + r;
      float M = fmaxf(fmaxf(rmax[0][row], rmax[1][row]), fmaxf(rmax[2][row], rmax[3][row]));
      M = fmaxf(M, fmaxf(fmaxf(rmax[4][row], rmax[5][row]), fmaxf(rmax[6][row], rmax[7][row])));
      Mrow[m][r] = M;
      rst[m][r] = 0.0f;
    }
#pragma unroll
  for (int m = 0; m < 2; ++m)
#pragma unroll
    for (int r = 0; r < 4; ++r)
#pragma unroll
      for (int n = 0; n < 8; ++n) {
        float w = (mkv[n] != 0.0f) ? __expf(acc[m][n][r] - Mrow[m][r]) : 0.0f;
        acc[m][n][r] = w;
        rst[m][r] += w;
      }
#pragma unroll
  for (int m = 0; m < 2; ++m)
#pragma unroll
    for (int r = 0; r < 4; ++r) {
      float v = rst[m][r];
      v += __shfl_xor(v, 1);
      v += __shfl_xor(v, 2);
      v += __shfl_xor(v, 4);
      v += __shfl_xor(v, 8);
      rst[m][r] = v;
    }
  if (l15 == 0) {
#pragma unroll
    for (int m = 0; m < 2; ++m)
#pragma unroll
      for (int r = 0; r < 4; ++r)
        rsum[kw][qw * 32 + 16 * m + quad * 4 + r] = rst[m][r];
  }
  __syncthreads();

#pragma unroll
  for (int m = 0; m < 2; ++m)
#pragma unroll
    for (int r = 0; r < 4; ++r) {
      const int row = qw * 32 + 16 * m + quad * 4 + r;
      float S = rsum[0][row] + rsum[1][row] + rsum[2][row] + rsum[3][row] +
                rsum[4][row] + rsum[5][row] + rsum[6][row] + rsum[7][row];
      const float inv = 1.0f / (S + 1e-13f);
#pragma unroll
      for (int n = 0; n < 8; ++n)
        KU.At[row][kw * 128 + 16 * n + l15] = (_Float16)(acc[m][n][r] * inv);
    }
  __syncthreads();

  {
    const int orow = tid >> 4;
    const int oc   = (tid & 15) * 8;
    _Float16* gp = alpha + ((size_t)(b * L_ + qblk * 64 + orow)) * L_;
#pragma unroll
    for (int p = 0; p < 8; ++p)
      *(half8*)(gp + oc + p * 128) = *(half8*)&KU.At[orow][oc + p * 128];
  }
}

// ---------------------------------------------------------------------------
// phase2: out = alpha @ x. grid (32, 32) swizzled. R6 LDS layout exactly.
// 512 threads = 8 waves (qw 0..1, dw 0..3); wave tile 32q x 128d.
// V transposed into LDS via fp32 float2-pair register packing (R1 pattern).
// ---------------------------------------------------------------------------
__global__ __launch_bounds__(512, 3) void sam_pv5(
    const float* __restrict__ x, const _Float16* __restrict__ alpha,
    float* __restrict__ out)
{
  const int id  = blockIdx.y * 32 + blockIdx.x;   // 1024 blocks
  const int wid = (id & 7) * 128 + (id >> 3);     // bijective XCD chunking
  const int b   = wid >> 5;
  const int rr  = wid & 31;
  const int qb  = rr >> 1;           // 0..15 -> 64 q rows
  const int dh  = rr & 1;            // d half: 512 cols
  const int tid  = threadIdx.x;
  const int wave = tid >> 6;
  const int lane = tid & 63;
  const int qw   = wave >> 2;        // 0..1 -> 32 q rows
  const int dw   = wave & 3;         // 0..3 -> 128 d cols
  const int l15  = lane & 15;
  const int quad = lane >> 4;

  __shared__ _Float16 Vs[512][40];   // Vs[d_local][k], stride 40 fp16 = 80 B
  __shared__ _Float16 As[64][40];    // alpha tile [q][k]

  f32x4 acc[2][8];
#pragma unroll
  for (int m = 0; m < 2; ++m)
#pragma unroll
    for (int n = 0; n < 8; ++n)
#pragma unroll
      for (int r = 0; r < 4; ++r) acc[m][n][r] = 0.0f;

  const int d0 = (tid & 255) * 2;    // V staging: 2 adjacent d rows/thread
  const int kh = tid >> 8;           // 16-key half

  for (int kc = 0; kc < 32; ++kc) {  // 32 key chunks of 32
    if (tid < 256) {                 // alpha tile 64q x 32k
      const int ar = tid >> 2, ac = tid & 3;
      *(half8*)&As[ar][ac * 8] =
          *(const half8*)(alpha + ((size_t)(b * L_ + qb * 64 + ar)) * L_ + kc * 32 + ac * 8);
    }
    {                                // V^T tile: 16k x 2d fp32->fp16 transpose
      const float* vp = x + ((size_t)(b * L_ + kc * 32 + kh * 16)) * D_ + dh * 512 + d0;
      half8 a0, a1, c0, c1;
#pragma unroll
      for (int kk = 0; kk < 8; ++kk) {
        float2 v = *(const float2*)(vp + (size_t)kk * D_);
        a0[kk] = (_Float16)v.x; c0[kk] = (_Float16)v.y;
      }
#pragma unroll
      for (int kk = 0; kk < 8; ++kk) {
        float2 v = *(const float2*)(vp + (size_t)(kk + 8) * D_);
        a1[kk] = (_Float16)v.x; c1[kk] = (_Float16)v.y;
      }
      *(half8*)&Vs[d0    ][kh * 16    ] = a0;
      *(half8*)&Vs[d0    ][kh * 16 + 8] = a1;
      *(half8*)&Vs[d0 + 1][kh * 16    ] = c0;
      *(half8*)&Vs[d0 + 1][kh * 16 + 8] = c1;
    }
    __syncthreads();
    half8 af[2], bf[8];
#pragma unroll
    for (int m = 0; m < 2; ++m)
      af[m] = *(half8*)&As[qw * 32 + 16 * m + l15][quad * 8];
#pragma unroll
    for (int n = 0; n < 8; ++n)
      bf[n] = *(half8*)&Vs[dw * 128 + 16 * n + l15][quad * 8];
#pragma unroll
    for (int m = 0; m < 2; ++m)
#pragma unroll
      for (int n = 0; n < 8; ++n)
        acc[m][n] = __builtin_amdgcn_mfma_f32_16x16x32_f16(af[m], bf[n], acc[m][n], 0, 0, 0);
    __syncthreads();
  }

#pragma unroll
  for (int m = 0; m < 2; ++m)
#pragma unroll
    for (int r = 0; r < 4; ++r) {
      const int gq = qb * 64 + qw * 32 + 16 * m + quad * 4 + r;
      float* op = out + (size_t)(b * L_ + gq) * D_ + dh * 512 + dw * 128;
#pragma unroll
      for (int n = 0; n < 8; ++n) op[16 * n + l15] = acc[m][n][r];
    }
}

// ===========================================================================
// FALLBACK PATH (R1, proven): used when ws_size < 64 MB
// ===========================================================================

__global__ __launch_bounds__(256, 2) void sam_scores_softmax(
    const float* __restrict__ x, const int* __restrict__ xmask,
    float* __restrict__ out)
{
  const int qblk = blockIdx.x;
  const int b    = blockIdx.y;
  const int tid  = threadIdx.x;
  const int wave = tid >> 6;
  const int lane = tid & 63;
  const int qh   = wave >> 1;
  const int kh   = wave & 1;
  const int l15  = lane & 15;
  const int quad = lane >> 4;

  __shared__ _Float16 Qs[128][72];
  __shared__ _Float16 Ks[256][72];
  __shared__ float msk[256];
  __shared__ float tmax[2][128];
  __shared__ float tsum[2][128];
  __shared__ float mrun[128];
  __shared__ float lrun[128];
  __shared__ float mtile[4][128];

  if (tid < 128) { mrun[tid] = 0.0f; lrun[tid] = 0.0f; }

  const float* xb = x + (size_t)b * L_ * D_;

  for (int kt = 0; kt < 4; ++kt) {
    msk[tid] = (float)xmask[b * L_ + kt * 256 + tid];

    f32x4 acc[4][8];
#pragma unroll
    for (int m = 0; m < 4; ++m)
#pragma unroll
      for (int n = 0; n < 8; ++n)
#pragma unroll
        for (int r = 0; r < 4; ++r) acc[m][n][r] = 0.0f;

    for (int dc = 0; dc < 16; ++dc) {
      {
        const int row = tid >> 1, cb = (tid & 1) * 32;
        const float* src = xb + (size_t)(qblk * 128 + row) * D_ + dc * 64 + cb;
#pragma unroll
        for (int i = 0; i < 4; ++i)
          *(half8*)&Qs[row][cb + i * 8] = cvt8(src + i * 8);
      }
      {
        const float* src = xb + (size_t)(kt * 256 + tid) * D_ + dc * 64;
#pragma unroll
        for (int i = 0; i < 8; ++i)
          *(half8*)&Ks[tid][i * 8] = cvt8(src + i * 8);
      }
      __syncthreads();
#pragma unroll
      for (int ks = 0; ks < 2; ++ks) {
        half8 af[4], bf[8];
#pragma unroll
        for (int m = 0; m < 4; ++m)
          af[m] = *(half8*)&Qs[qh * 64 + 16 * m + l15][ks * 32 + quad * 8];
#pragma unroll
        for (int n = 0; n < 8; ++n)
          bf[n] = *(half8*)&Ks[kh * 128 + 16 * n + l15][ks * 32 + quad * 8];
#pragma unroll
        for (int m = 0; m < 4; ++m)
#pragma unroll
          for (int n = 0; n < 8; ++n)
            acc[m][n] = __builtin_amdgcn_mfma_f32_16x16x32_f16(af[m], bf[n], acc[m][n], 0, 0, 0);
      }
      __syncthreads();
    }

    float mkv[8];
#pragma unroll
    for (int n = 0; n < 8; ++n) mkv[n] = msk[kh * 128 + 16 * n + l15];

    float rstat[4][4];
#pragma unroll
    for (int m = 0; m < 4; ++m)
#pragma unroll
      for (int r = 0; r < 4; ++r) rstat[m][r] = 0.0f;

#pragma unroll
    for (int m = 0; m < 4; ++m)
#pragma unroll
      for (int r = 0; r < 4; ++r) {
        const int gq = qblk * 128 + qh * 64 + 16 * m + quad * 4 + r;
#pragma unroll
        for (int n = 0; n < 8; ++n) {
          const int gk = kt * 256 + kh * 128 + 16 * n + l15;
          float v = acc[m][n][r];
          if (gq == gk) v = 0.0f;
          v = (mkv[n] != 0.0f) ? v : 0.0f;
          acc[m][n][r] = v;
          rstat[m][r] = fmaxf(rstat[m][r], v);
        }
      }
#pragma unroll
    for (int m = 0; m < 4; ++m)
#pragma unroll
      for (int r = 0; r < 4; ++r) {
        float v = rstat[m][r];
        v = fmaxf(v, __shfl_xor(v, 1));
        v = fmaxf(v, __shfl_xor(v, 2));
        v = fmaxf(v, __shfl_xor(v, 4));
        v = fmaxf(v, __shfl_xor(v, 8));
        rstat[m][r] = v;
      }
    if (l15 == 0) {
#pragma unroll
      for (int m = 0; m < 4; ++m)
#pragma unroll
        for (int r = 0; r < 4; ++r)
          tmax[kh][qh * 64 + 16 * m + quad * 4 + r] = rstat[m][r];
    }
    __syncthreads();

    float mnew[4][4];
#pragma unroll
    for (int m = 0; m < 4; ++m)
#pragma unroll
      for (int r = 0; r < 4; ++r) {
        const int row = qh * 64 + 16 * m + quad * 4 + r;
        mnew[m][r] = fmaxf(mrun[row], fmaxf(tmax[0][row], tmax[1][row]));
        rstat[m][r] = 0.0f;
      }
#pragma unroll
    for (int m = 0; m < 4; ++m)
#pragma unroll
      for (int r = 0; r < 4; ++r)
#pragma unroll
        for (int n = 0; n < 8; ++n) {
          float w = (mkv[n] != 0.0f) ? __expf(acc[m][n][r] - mnew[m][r]) : 0.0f;
          acc[m][n][r] = w;
          rstat[m][r] += w;
        }
#pragma unroll
    for (int m = 0; m < 4; ++m)
#pragma unroll
      for (int r = 0; r < 4; ++r) {
        float v = rstat[m][r];
        v += __shfl_xor(v, 1);
        v += __shfl_xor(v, 2);
        v += __shfl_xor(v, 4);
        v += __shfl_xor(v, 8);
        rstat[m][r] = v;
      }
    if (l15 == 0) {
#pragma unroll
      for (int m = 0; m < 4; ++m)
#pragma unroll
        for (int r = 0; r < 4; ++r)
          tsum[kh][qh * 64 + 16 * m + quad * 4 + r] = rstat[m][r];
    }
    __syncthreads();

    if (kh == 0 && l15 == 0) {
#pragma unroll
      for (int m = 0; m < 4; ++m)
#pragma unroll
        for (int r = 0; r < 4; ++r) {
          const int row = qh * 64 + 16 * m + quad * 4 + r;
          const float mo = mrun[row];
          const float mn = mnew[m][r];
          lrun[row] = lrun[row] * __expf(mo - mn) + tsum[0][row] + tsum[1][row];
          mrun[row] = mn;
          mtile[kt][row] = mn;
        }
    }
#pragma unroll
    for (int m = 0; m < 4; ++m)
#pragma unroll
      for (int r = 0; r < 4; ++r) {
        const int gq = qblk * 128 + qh * 64 + 16 * m + quad * 4 + r;
        _Float16* wp = (_Float16*)((char*)out + (size_t)(b * L_ + gq) * (D_ * 4));
#pragma unroll
        for (int n = 0; n < 8; ++n)
          wp[kt * 256 + kh * 128 + 16 * n + l15] = (_Float16)acc[m][n][r];
      }
    __syncthreads();
  }

  __threadfence();
  __syncthreads();
  {
    const int row = tid >> 1, hf = tid & 1;
    const int gq = qblk * 128 + row;
    char* rowp = (char*)out + (size_t)(b * L_ + gq) * (D_ * 4);
    const float Mv  = mrun[row];
    const float inv = 1.0f / (lrun[row] + 1e-13f);
    const float sc0 = __expf(mtile[hf * 2    ][row] - Mv) * inv;
    const float sc1 = __expf(mtile[hf * 2 + 1][row] - Mv) * inv;
    for (int i = 0; i < 64; ++i) {
      const int col = hf * 512 + i * 8;
      const float s = (i < 32) ? sc0 : sc1;
      half8 v = *(half8*)(rowp + col * 2);
#pragma unroll
      for (int j = 0; j < 8; ++j) v[j] = (_Float16)((float)v[j] * s);
      *(half8*)(rowp + col * 2) = v;
      *(half8*)(rowp + 2048 + col * 2) = v;
    }
  }
}

__global__ __launch_bounds__(512, 2) void sam_pv(
    const float* __restrict__ x, float* __restrict__ out)
{
  const int q128 = blockIdx.x >> 1;
  const int dh   = blockIdx.x & 1;
  const int b    = blockIdx.y;
  const int tid  = threadIdx.x;
  const int wave = tid >> 6;
  const int lane = tid & 63;
  const int qh   = wave >> 2;
  const int dq   = wave & 3;
  const int l15  = lane & 15;
  const int quad = lane >> 4;

  __shared__ _Float16 Vs[512][40];
  __shared__ _Float16 As[128][40];

  f32x4 acc[4][8];
#pragma unroll
  for (int m = 0; m < 4; ++m)
#pragma unroll
    for (int n = 0; n < 8; ++n)
#pragma unroll
      for (int r = 0; r < 4; ++r) acc[m][n][r] = 0.0f;

  const int arow  = tid >> 2, aoct = tid & 3;
  const int d0    = (tid & 255) * 2;
  const int khalf = tid >> 8;

  for (int kc = 0; kc < 32; ++kc) {
    *(half8*)&As[arow][aoct * 8] =
        *(const half8*)((const char*)out +
                        (size_t)(b * L_ + q128 * 128 + arow) * (D_ * 4) +
                        dh * 2048 + kc * 64 + aoct * 16);
    {
      const float* vs = x + (size_t)(b * L_ + kc * 32 + khalf * 16) * D_ + dh * 512 + d0;
      half8 a0, a1, c0, c1;
#pragma unroll
      for (int kk = 0; kk < 8; ++kk) {
        float2 v = *(const float2*)(vs + (size_t)kk * D_);
        a0[kk] = (_Float16)v.x; c0[kk] = (_Float16)v.y;
      }
#pragma unroll
      for (int kk = 0; kk < 8; ++kk) {
        float2 v = *(const float2*)(vs + (size_t)(kk + 8) * D_);
        a1[kk] = (_Float16)v.x; c1[kk] = (_Float16)v.y;
      }
      *(half8*)&Vs[d0    ][khalf * 16    ] = a0;
      *(half8*)&Vs[d0    ][khalf * 16 + 8] = a1;
      *(half8*)&Vs[d0 + 1][khalf * 16    ] = c0;
      *(half8*)&Vs[d0 + 1][khalf * 16 + 8] = c1;
    }
    __syncthreads();
    half8 af[4], bf[8];
#pragma unroll
    for (int m = 0; m < 4; ++m)
      af[m] = *(half8*)&As[qh * 64 + 16 * m + l15][quad * 8];
#pragma unroll
    for (int n = 0; n < 8; ++n)
      bf[n] = *(half8*)&Vs[dq * 128 + 16 * n + l15][quad * 8];
#pragma unroll
    for (int m = 0; m < 4; ++m)
#pragma unroll
      for (int n = 0; n < 8; ++n)
        acc[m][n] = __builtin_amdgcn_mfma_f32_16x16x32_f16(af[m], bf[n], acc[m][n], 0, 0, 0);
    __syncthreads();
  }

#pragma unroll
  for (int m = 0; m < 4; ++m)
#pragma unroll
    for (int r = 0; r < 4; ++r) {
      const int gq = q128 * 128 + qh * 64 + 16 * m + quad * 4 + r;
      float* op = out + (size_t)(b * L_ + gq) * D_ + dh * 512 + dq * 128;
#pragma unroll
      for (int n = 0; n < 8; ++n) op[16 * n + l15] = acc[m][n][r];
    }
}

extern "C" void kernel_launch(void* const* d_in, const int* in_sizes, int n_in,
                              void* d_out, int out_size, void* d_ws, size_t ws_size,
                              hipStream_t stream) {
  const float* x  = (const float*)d_in[0];
  const int*   xm = (const int*)d_in[1];
  float* out = (float*)d_out;
  (void)in_sizes; (void)n_in; (void)out_size;

  if (ws_size >= (size_t)64 * 1024 * 1024) {
    _Float16* alp = (_Float16*)d_ws;
    sam_scores5<<<dim3(16, 32), 1024, 0, stream>>>(x, xm, alp);
    sam_pv5<<<dim3(32, 32), 512, 0, stream>>>(x, alp, out);
  } else {
    sam_scores_softmax<<<dim3(8, 32), 256, 0, stream>>>(x, xm, out);
    sam_pv<<<dim3(16, 32), 512, 0, stream>>>(x, out);
  }
}

// Round 7
// 439.806 us; speedup vs baseline: 1.1222x; 1.1222x over previous
//
#include <hip/hip_runtime.h>

// SelfAttnMatch: B=32, L=1024, D=1024, fp32 in/out.
//   scores = x @ x^T (diag zeroed); t = scores*mask; a = softmax(t)*mask;
//   alpha = a / (sum(a)+1e-13); out = alpha @ x
//
// R9 = R6 (best, 447us: cvt + scores3 + pv2, XCD swizzle) + pv2 stride fix:
//   Vs/As row stride 40 -> 44 fp16 (88 B). Write-phase banks go
//   {0,8,16,24}x4 (4-way, 1.99e7 conflicts) -> {0,4..28}x2 (free);
//   reads stay free (22*l15 mod 32 = 16 distinct starts). LDS 45->49.5 KB,
//   still 3 blocks/CU. No access-pattern change - stride only.
// R8 post-mortem: deleting cvt cost +61us in pv5 (fp32 V-gather doubles
//   bytes on the latency-critical path); fp16 intermediate restored.
// R7 post-mortem: row permutation fixed writes but broke reads (2.83e7).
// Fallback path (small ws): R1 kernels verbatim.

typedef _Float16 half8 __attribute__((ext_vector_type(8)));
typedef float f32x4 __attribute__((ext_vector_type(4)));

#define L_ 1024
#define D_ 1024

__device__ __forceinline__ half8 cvt8(const float* src) {
  float4 a = *(const float4*)src;
  float4 c = *(const float4*)(src + 4);
  half8 h;
  h[0] = (_Float16)a.x; h[1] = (_Float16)a.y; h[2] = (_Float16)a.z; h[3] = (_Float16)a.w;
  h[4] = (_Float16)c.x; h[5] = (_Float16)c.y; h[6] = (_Float16)c.z; h[7] = (_Float16)c.w;
  return h;
}

// ===========================================================================
// FAST PATH
// ===========================================================================

// phase0: fp32 -> fp16, 32 elems/thread, grid 4096x256 covers 32*1024*1024
__global__ void sam_cvt(const float* __restrict__ x, _Float16* __restrict__ xh) {
  const size_t base = ((size_t)blockIdx.x * 256 + threadIdx.x) * 32;
  const float* src = x + base;
  _Float16* dst = xh + base;
#pragma unroll
  for (int i = 0; i < 4; ++i)
    *(half8*)(dst + i * 8) = cvt8(src + i * 8);
}

// ---------------------------------------------------------------------------
// phase1 (R3-proven + XCD swizzle): full-row scores + softmax -> alpha fp16.
// grid (16, 32); 1024 threads = 16 waves in a 2x8 (qw,kw) grid.
// Block tile 64q x 1024k. Swizzle: XCD c gets wid [64c,64c+64) = 4 whole b's.
// ---------------------------------------------------------------------------
__global__ __launch_bounds__(1024, 4) void sam_scores3(
    const _Float16* __restrict__ xh, const int* __restrict__ xmask,
    _Float16* __restrict__ alpha)
{
  const int id   = blockIdx.y * 16 + blockIdx.x;   // 512 blocks
  const int wid  = (id & 7) * 64 + (id >> 3);      // bijective XCD chunking
  const int qblk = wid & 15;
  const int b    = wid >> 4;
  const int tid  = threadIdx.x;
  const int wave = tid >> 6;
  const int lane = tid & 63;
  const int qw   = wave >> 3;        // 0..1 -> 32 q rows
  const int kw   = wave & 7;         // 0..7 -> 128 k cols
  const int l15  = lane & 15;
  const int quad = lane >> 4;

  __shared__ _Float16 Qs[64][72];    // 9 KB (stride 72 = conflict-free b128)
  __shared__ union KsAt {
    _Float16 Ks[1024][72];           // 144 KB staging view
    _Float16 At[64][1032];           // 132 KB alpha-transpose view (epilogue)
  } KU;
  __shared__ float rmax[8][64];      // 2 KB
  __shared__ float rsum[8][64];      // 2 KB

  const _Float16* xb = xh + (size_t)b * L_ * D_;
  const int srow = tid >> 3;             // staging row (8 thr/row)
  const int scol = (tid & 7) * 8;        // 16-B chunk

  f32x4 acc[2][8];
#pragma unroll
  for (int m = 0; m < 2; ++m)
#pragma unroll
    for (int n = 0; n < 8; ++n)
#pragma unroll
      for (int r = 0; r < 4; ++r) acc[m][n][r] = 0.0f;

  for (int dc = 0; dc < 16; ++dc) {      // D in chunks of 64
    if (tid < 512)
      *(half8*)&Qs[srow][scol] =
          *(const half8*)(xb + (size_t)(qblk * 64 + srow) * D_ + dc * 64 + scol);
#pragma unroll
    for (int i = 0; i < 8; ++i)
      *(half8*)&KU.Ks[srow + 128 * i][scol] =
          *(const half8*)(xb + (size_t)(srow + 128 * i) * D_ + dc * 64 + scol);
    __syncthreads();
#pragma unroll
    for (int ks = 0; ks < 2; ++ks) {
      half8 af[2], bf[8];
#pragma unroll
      for (int m = 0; m < 2; ++m)
        af[m] = *(half8*)&Qs[qw * 32 + 16 * m + l15][ks * 32 + quad * 8];
#pragma unroll
      for (int n = 0; n < 8; ++n)
        bf[n] = *(half8*)&KU.Ks[kw * 128 + 16 * n + l15][ks * 32 + quad * 8];
#pragma unroll
      for (int m = 0; m < 2; ++m)
#pragma unroll
        for (int n = 0; n < 8; ++n)
          acc[m][n] = __builtin_amdgcn_mfma_f32_16x16x32_f16(af[m], bf[n], acc[m][n], 0, 0, 0);
    }
    __syncthreads();
  }

  // ---- epilogue: diag zero, mask, full-row softmax, normalized store ----
  float mkv[8];
#pragma unroll
  for (int n = 0; n < 8; ++n)
    mkv[n] = (float)xmask[b * L_ + kw * 128 + 16 * n + l15];

  float rst[2][4];
#pragma unroll
  for (int m = 0; m < 2; ++m)
#pragma unroll
    for (int r = 0; r < 4; ++r) rst[m][r] = 0.0f;

#pragma unroll
  for (int m = 0; m < 2; ++m)
#pragma unroll
    for (int r = 0; r < 4; ++r) {
      const int gq = qblk * 64 + qw * 32 + 16 * m + quad * 4 + r;
#pragma unroll
      for (int n = 0; n < 8; ++n) {
        const int gk = kw * 128 + 16 * n + l15;
        float v = acc[m][n][r];
        if (gq == gk) v = 0.0f;
        v = (mkv[n] != 0.0f) ? v : 0.0f;
        acc[m][n][r] = v;
        rst[m][r] = fmaxf(rst[m][r], v);
      }
    }
#pragma unroll
  for (int m = 0; m < 2; ++m)
#pragma unroll
    for (int r = 0; r < 4; ++r) {
      float v = rst[m][r];
      v = fmaxf(v, __shfl_xor(v, 1));
      v = fmaxf(v, __shfl_xor(v, 2));
      v = fmaxf(v, __shfl_xor(v, 4));
      v = fmaxf(v, __shfl_xor(v, 8));
      rst[m][r] = v;
    }
  if (l15 == 0) {
#pragma unroll
    for (int m = 0; m < 2; ++m)
#pragma unroll
      for (int r = 0; r < 4; ++r)
        rmax[kw][qw * 32 + 16 * m + quad * 4 + r] = rst[m][r];
  }
  __syncthreads();

  float Mrow[2][4];
#pragma unroll
  for (int m = 0; m < 2; ++m)
#pragma unroll
    for (int r = 0; r < 4; ++r) {
      const int row = qw * 32 + 16 * m + quad * 4 + r;
      float M = fmaxf(fmaxf(rmax[0][row], rmax[1][row]), fmaxf(rmax[2][row], rmax[3][row]));
      M = fmaxf(M, fmaxf(fmaxf(rmax[4][row], rmax[5][row]), fmaxf(rmax[6][row], rmax[7][row])));
      Mrow[m][r] = M;
      rst[m][r] = 0.0f;
    }
#pragma unroll
  for (int m = 0; m < 2; ++m)
#pragma unroll
    for (int r = 0; r < 4; ++r)
#pragma unroll
      for (int n = 0; n < 8; ++n) {
        float w = (mkv[n] != 0.0f) ? __expf(acc[m][n][r] - Mrow[m][r]) : 0.0f;
        acc[m][n][r] = w;
        rst[m][r] += w;
      }
#pragma unroll
  for (int m = 0; m < 2; ++m)
#pragma unroll
    for (int r = 0; r < 4; ++r) {
      float v = rst[m][r];
      v += __shfl_xor(v, 1);
      v += __shfl_xor(v, 2);
      v += __shfl_xor(v, 4);
      v += __shfl_xor(v, 8);
      rst[m][r] = v;
    }
  if (l15 == 0) {
#pragma unroll
    for (int m = 0; m < 2; ++m)
#pragma unroll
      for (int r = 0; r < 4; ++r)
        rsum[kw][qw * 32 + 16 * m + quad * 4 + r] = rst[m][r];
  }
  __syncthreads();

#pragma unroll
  for (int m = 0; m < 2; ++m)
#pragma unroll
    for (int r = 0; r < 4; ++r) {
      const int row = qw * 32 + 16 * m + quad * 4 + r;
      float S = rsum[0][row] + rsum[1][row] + rsum[2][row] + rsum[3][row] +
                rsum[4][row] + rsum[5][row] + rsum[6][row] + rsum[7][row];
      const float inv = 1.0f / (S + 1e-13f);
#pragma unroll
      for (int n = 0; n < 8; ++n)
        KU.At[row][kw * 128 + 16 * n + l15] = (_Float16)(acc[m][n][r] * inv);
    }
  __syncthreads();

  {
    const int orow = tid >> 4;
    const int oc   = (tid & 15) * 8;
    _Float16* gp = alpha + ((size_t)(b * L_ + qblk * 64 + orow)) * L_;
#pragma unroll
    for (int p = 0; p < 8; ++p)
      *(half8*)(gp + oc + p * 128) = *(half8*)&KU.At[orow][oc + p * 128];
  }
}

// ---------------------------------------------------------------------------
// phase2 (R6 + stride-44 bank fix): out = alpha @ x. grid (32, 32) swizzled.
// 512 threads = 8 waves (qw 0..1, dw 0..3); wave tile 32q x 128d.
// V transposed into LDS via fp16-pair register packing.
// Row stride 44 fp16 = 88 B: write starts 12t mod 32 (8 distinct, 2/bank,
// free); read starts 22*l15 mod 32 (16 distinct even, 2/bank, free).
// ---------------------------------------------------------------------------
__global__ __launch_bounds__(512, 3) void sam_pv2(
    const _Float16* __restrict__ xh, const _Float16* __restrict__ alpha,
    float* __restrict__ out)
{
  const int id  = blockIdx.y * 32 + blockIdx.x;   // 1024 blocks
  const int wid = (id & 7) * 128 + (id >> 3);     // bijective XCD chunking
  const int b   = wid >> 5;
  const int rr  = wid & 31;
  const int qb  = rr >> 1;           // 0..15 -> 64 q rows
  const int dh  = rr & 1;            // d half: 512 cols
  const int tid  = threadIdx.x;
  const int wave = tid >> 6;
  const int lane = tid & 63;
  const int qw   = wave >> 2;        // 0..1 -> 32 q rows
  const int dw   = wave & 3;         // 0..3 -> 128 d cols
  const int l15  = lane & 15;
  const int quad = lane >> 4;

  __shared__ _Float16 Vs[512][44];   // stride 44 fp16 = 88 B (bank fix)
  __shared__ _Float16 As[64][44];    // alpha tile [q][k]

  f32x4 acc[2][8];
#pragma unroll
  for (int m = 0; m < 2; ++m)
#pragma unroll
    for (int n = 0; n < 8; ++n)
#pragma unroll
      for (int r = 0; r < 4; ++r) acc[m][n][r] = 0.0f;

  const int d0 = (tid & 255) * 2;    // V staging: 2 adjacent d rows/thread
  const int kh = tid >> 8;           // 16-key half

  for (int kc = 0; kc < 32; ++kc) {  // 32 key chunks of 32
    if (tid < 256) {                 // alpha tile 64q x 32k
      const int ar = tid >> 2, ac = tid & 3;
      *(half8*)&As[ar][ac * 8] =
          *(const half8*)(alpha + ((size_t)(b * L_ + qb * 64 + ar)) * L_ + kc * 32 + ac * 8);
    }
    {                                // V^T tile: 16k x 2d register transpose
      const _Float16* vp = xh + ((size_t)(b * L_ + kc * 32 + kh * 16)) * D_ + dh * 512 + d0;
      half8 a0, a1, c0, c1;
#pragma unroll
      for (int kk = 0; kk < 8; ++kk) {
        union { unsigned int u; _Float16 h[2]; } cv;
        cv.u = *(const unsigned int*)(vp + (size_t)kk * D_);
        a0[kk] = cv.h[0]; c0[kk] = cv.h[1];
      }
#pragma unroll
      for (int kk = 0; kk < 8; ++kk) {
        union { unsigned int u; _Float16 h[2]; } cv;
        cv.u = *(const unsigned int*)(vp + (size_t)(kk + 8) * D_);
        a1[kk] = cv.h[0]; c1[kk] = cv.h[1];
      }
      *(half8*)&Vs[d0    ][kh * 16    ] = a0;
      *(half8*)&Vs[d0    ][kh * 16 + 8] = a1;
      *(half8*)&Vs[d0 + 1][kh * 16    ] = c0;
      *(half8*)&Vs[d0 + 1][kh * 16 + 8] = c1;
    }
    __syncthreads();
    half8 af[2], bf[8];
#pragma unroll
    for (int m = 0; m < 2; ++m)
      af[m] = *(half8*)&As[qw * 32 + 16 * m + l15][quad * 8];
#pragma unroll
    for (int n = 0; n < 8; ++n)
      bf[n] = *(half8*)&Vs[dw * 128 + 16 * n + l15][quad * 8];
#pragma unroll
    for (int m = 0; m < 2; ++m)
#pragma unroll
      for (int n = 0; n < 8; ++n)
        acc[m][n] = __builtin_amdgcn_mfma_f32_16x16x32_f16(af[m], bf[n], acc[m][n], 0, 0, 0);
    __syncthreads();
  }

#pragma unroll
  for (int m = 0; m < 2; ++m)
#pragma unroll
    for (int r = 0; r < 4; ++r) {
      const int gq = qb * 64 + qw * 32 + 16 * m + quad * 4 + r;
      float* op = out + (size_t)(b * L_ + gq) * D_ + dh * 512 + dw * 128;
#pragma unroll
      for (int n = 0; n < 8; ++n) op[16 * n + l15] = acc[m][n][r];
    }
}

// ===========================================================================
// FALLBACK PATH (R1, proven): used when ws_size < 128 MB
// ===========================================================================

__global__ __launch_bounds__(256, 2) void sam_scores_softmax(
    const float* __restrict__ x, const int* __restrict__ xmask,
    float* __restrict__ out)
{
  const int qblk = blockIdx.x;
  const int b    = blockIdx.y;
  const int tid  = threadIdx.x;
  const int wave = tid >> 6;
  const int lane = tid & 63;
  const int qh   = wave >> 1;
  const int kh   = wave & 1;
  const int l15  = lane & 15;
  const int quad = lane >> 4;

  __shared__ _Float16 Qs[128][72];
  __shared__ _Float16 Ks[256][72];
  __shared__ float msk[256];
  __shared__ float tmax[2][128];
  __shared__ float tsum[2][128];
  __shared__ float mrun[128];
  __shared__ float lrun[128];
  __shared__ float mtile[4][128];

  if (tid < 128) { mrun[tid] = 0.0f; lrun[tid] = 0.0f; }

  const float* xb = x + (size_t)b * L_ * D_;

  for (int kt = 0; kt < 4; ++kt) {
    msk[tid] = (float)xmask[b * L_ + kt * 256 + tid];

    f32x4 acc[4][8];
#pragma unroll
    for (int m = 0; m < 4; ++m)
#pragma unroll
      for (int n = 0; n < 8; ++n)
#pragma unroll
        for (int r = 0; r < 4; ++r) acc[m][n][r] = 0.0f;

    for (int dc = 0; dc < 16; ++dc) {
      {
        const int row = tid >> 1, cb = (tid & 1) * 32;
        const float* src = xb + (size_t)(qblk * 128 + row) * D_ + dc * 64 + cb;
#pragma unroll
        for (int i = 0; i < 4; ++i)
          *(half8*)&Qs[row][cb + i * 8] = cvt8(src + i * 8);
      }
      {
        const float* src = xb + (size_t)(kt * 256 + tid) * D_ + dc * 64;
#pragma unroll
        for (int i = 0; i < 8; ++i)
          *(half8*)&Ks[tid][i * 8] = cvt8(src + i * 8);
      }
      __syncthreads();
#pragma unroll
      for (int ks = 0; ks < 2; ++ks) {
        half8 af[4], bf[8];
#pragma unroll
        for (int m = 0; m < 4; ++m)
          af[m] = *(half8*)&Qs[qh * 64 + 16 * m + l15][ks * 32 + quad * 8];
#pragma unroll
        for (int n = 0; n < 8; ++n)
          bf[n] = *(half8*)&Ks[kh * 128 + 16 * n + l15][ks * 32 + quad * 8];
#pragma unroll
        for (int m = 0; m < 4; ++m)
#pragma unroll
          for (int n = 0; n < 8; ++n)
            acc[m][n] = __builtin_amdgcn_mfma_f32_16x16x32_f16(af[m], bf[n], acc[m][n], 0, 0, 0);
      }
      __syncthreads();
    }

    float mkv[8];
#pragma unroll
    for (int n = 0; n < 8; ++n) mkv[n] = msk[kh * 128 + 16 * n + l15];

    float rstat[4][4];
#pragma unroll
    for (int m = 0; m < 4; ++m)
#pragma unroll
      for (int r = 0; r < 4; ++r) rstat[m][r] = 0.0f;

#pragma unroll
    for (int m = 0; m < 4; ++m)
#pragma unroll
      for (int r = 0; r < 4; ++r) {
        const int gq = qblk * 128 + qh * 64 + 16 * m + quad * 4 + r;
#pragma unroll
        for (int n = 0; n < 8; ++n) {
          const int gk = kt * 256 + kh * 128 + 16 * n + l15;
          float v = acc[m][n][r];
          if (gq == gk) v = 0.0f;
          v = (mkv[n] != 0.0f) ? v : 0.0f;
          acc[m][n][r] = v;
          rstat[m][r] = fmaxf(rstat[m][r], v);
        }
      }
#pragma unroll
    for (int m = 0; m < 4; ++m)
#pragma unroll
      for (int r = 0; r < 4; ++r) {
        float v = rstat[m][r];
        v = fmaxf(v, __shfl_xor(v, 1));
        v = fmaxf(v, __shfl_xor(v, 2));
        v = fmaxf(v, __shfl_xor(v, 4));
        v = fmaxf(v, __shfl_xor(v, 8));
        rstat[m][r] = v;
      }
    if (l15 == 0) {
#pragma unroll
      for (int m = 0; m < 4; ++m)
#pragma unroll
        for (int r = 0; r < 4; ++r)
          tmax[kh][qh * 64 + 16 * m + quad * 4 + r] = rstat[m][r];
    }
    __syncthreads();

    float mnew[4][4];
#pragma unroll
    for (int m = 0; m < 4; ++m)
#pragma unroll
      for (int r = 0; r < 4; ++r) {
        const int row = qh * 64 + 16 * m + quad * 4 + r;
        mnew[m][r] = fmaxf(mrun[row], fmaxf(tmax[0][row], tmax[1][row]));
        rstat[m][r] = 0.0f;
      }
#pragma unroll
    for (int m = 0; m < 4; ++m)
#pragma unroll
      for (int r = 0; r < 4; ++r)
#pragma unroll
        for (int n = 0; n < 8; ++n) {
          float w = (mkv[n] != 0.0f) ? __expf(acc[m][n][r] - mnew[m][r]) : 0.0f;
          acc[m][n][r] = w;
          rstat[m][r] += w;
        }
#pragma unroll
    for (int m = 0; m < 4; ++m)
#pragma unroll
      for (int r = 0; r < 4; ++r) {
        float v = rstat[m][r];
        v += __shfl_xor(v, 1);
        v += __shfl_xor(v, 2);
        v += __shfl_xor(v, 4);
        v += __shfl_xor(v, 8);
        rstat[m][r] = v;
      }
    if (l15 == 0) {
#pragma unroll
      for (int m = 0; m < 4; ++m)
#pragma unroll
        for (int r = 0; r < 4; ++r)
          tsum[kh][qh * 64 + 16 * m + quad * 4 + r] = rstat[m][r];
    }
    __syncthreads();

    if (kh == 0 && l15 == 0) {
#pragma unroll
      for (int m = 0; m < 4; ++m)
#pragma unroll
        for (int r = 0; r < 4; ++r) {
          const int row = qh * 64 + 16 * m + quad * 4 + r;
          const float mo = mrun[row];
          const float mn = mnew[m][r];
          lrun[row] = lrun[row] * __expf(mo - mn) + tsum[0][row] + tsum[1][row];
          mrun[row] = mn;
          mtile[kt][row] = mn;
        }
    }
#pragma unroll
    for (int m = 0; m < 4; ++m)
#pragma unroll
      for (int r = 0; r < 4; ++r) {
        const int gq = qblk * 128 + qh * 64 + 16 * m + quad * 4 + r;
        _Float16* wp = (_Float16*)((char*)out + (size_t)(b * L_ + gq) * (D_ * 4));
#pragma unroll
        for (int n = 0; n < 8; ++n)
          wp[kt * 256 + kh * 128 + 16 * n + l15] = (_Float16)acc[m][n][r];
      }
    __syncthreads();
  }

  __threadfence();
  __syncthreads();
  {
    const int row = tid >> 1, hf = tid & 1;
    const int gq = qblk * 128 + row;
    char* rowp = (char*)out + (size_t)(b * L_ + gq) * (D_ * 4);
    const float Mv  = mrun[row];
    const float inv = 1.0f / (lrun[row] + 1e-13f);
    const float sc0 = __expf(mtile[hf * 2    ][row] - Mv) * inv;
    const float sc1 = __expf(mtile[hf * 2 + 1][row] - Mv) * inv;
    for (int i = 0; i < 64; ++i) {
      const int col = hf * 512 + i * 8;
      const float s = (i < 32) ? sc0 : sc1;
      half8 v = *(half8*)(rowp + col * 2);
#pragma unroll
      for (int j = 0; j < 8; ++j) v[j] = (_Float16)((float)v[j] * s);
      *(half8*)(rowp + col * 2) = v;
      *(half8*)(rowp + 2048 + col * 2) = v;
    }
  }
}

__global__ __launch_bounds__(512, 2) void sam_pv(
    const float* __restrict__ x, float* __restrict__ out)
{
  const int q128 = blockIdx.x >> 1;
  const int dh   = blockIdx.x & 1;
  const int b    = blockIdx.y;
  const int tid  = threadIdx.x;
  const int wave = tid >> 6;
  const int lane = tid & 63;
  const int qh   = wave >> 2;
  const int dq   = wave & 3;
  const int l15  = lane & 15;
  const int quad = lane >> 4;

  __shared__ _Float16 Vs[512][40];
  __shared__ _Float16 As[128][40];

  f32x4 acc[4][8];
#pragma unroll
  for (int m = 0; m < 4; ++m)
#pragma unroll
    for (int n = 0; n < 8; ++n)
#pragma unroll
      for (int r = 0; r < 4; ++r) acc[m][n][r] = 0.0f;

  const int arow  = tid >> 2, aoct = tid & 3;
  const int d0    = (tid & 255) * 2;
  const int khalf = tid >> 8;

  for (int kc = 0; kc < 32; ++kc) {
    *(half8*)&As[arow][aoct * 8] =
        *(const half8*)((const char*)out +
                        (size_t)(b * L_ + q128 * 128 + arow) * (D_ * 4) +
                        dh * 2048 + kc * 64 + aoct * 16);
    {
      const float* vs = x + (size_t)(b * L_ + kc * 32 + khalf * 16) * D_ + dh * 512 + d0;
      half8 a0, a1, c0, c1;
#pragma unroll
      for (int kk = 0; kk < 8; ++kk) {
        float2 v = *(const float2*)(vs + (size_t)kk * D_);
        a0[kk] = (_Float16)v.x; c0[kk] = (_Float16)v.y;
      }
#pragma unroll
      for (int kk = 0; kk < 8; ++kk) {
        float2 v = *(const float2*)(vs + (size_t)(kk + 8) * D_);
        a1[kk] = (_Float16)v.x; c1[kk] = (_Float16)v.y;
      }
      *(half8*)&Vs[d0    ][khalf * 16    ] = a0;
      *(half8*)&Vs[d0    ][khalf * 16 + 8] = a1;
      *(half8*)&Vs[d0 + 1][khalf * 16    ] = c0;
      *(half8*)&Vs[d0 + 1][khalf * 16 + 8] = c1;
    }
    __syncthreads();
    half8 af[4], bf[8];
#pragma unroll
    for (int m = 0; m < 4; ++m)
      af[m] = *(half8*)&As[qh * 64 + 16 * m + l15][quad * 8];
#pragma unroll
    for (int n = 0; n < 8; ++n)
      bf[n] = *(half8*)&Vs[dq * 128 + 16 * n + l15][quad * 8];
#pragma unroll
    for (int m = 0; m < 4; ++m)
#pragma unroll
      for (int n = 0; n < 8; ++n)
        acc[m][n] = __builtin_amdgcn_mfma_f32_16x16x32_f16(af[m], bf[n], acc[m][n], 0, 0, 0);
    __syncthreads();
  }

#pragma unroll
  for (int m = 0; m < 4; ++m)
#pragma unroll
    for (int r = 0; r < 4; ++r) {
      const int gq = q128 * 128 + qh * 64 + 16 * m + quad * 4 + r;
      float* op = out + (size_t)(b * L_ + gq) * D_ + dh * 512 + dq * 128;
#pragma unroll
      for (int n = 0; n < 8; ++n) op[16 * n + l15] = acc[m][n][r];
    }
}

extern "C" void kernel_launch(void* const* d_in, const int* in_sizes, int n_in,
                              void* d_out, int out_size, void* d_ws, size_t ws_size,
                              hipStream_t stream) {
  const float* x  = (const float*)d_in[0];
  const int*   xm = (const int*)d_in[1];
  float* out = (float*)d_out;
  (void)in_sizes; (void)n_in; (void)out_size;

  if (ws_size >= (size_t)128 * 1024 * 1024) {
    _Float16* xhp = (_Float16*)d_ws;
    _Float16* alp = (_Float16*)((char*)d_ws + (size_t)64 * 1024 * 1024);
    sam_cvt<<<4096, 256, 0, stream>>>(x, xhp);
    sam_scores3<<<dim3(16, 32), 1024, 0, stream>>>(xhp, xm, alp);
    sam_pv2<<<dim3(32, 32), 512, 0, stream>>>(xhp, alp, out);
  } else {
    sam_scores_softmax<<<dim3(8, 32), 256, 0, stream>>>(x, xm, out);
    sam_pv<<<dim3(16, 32), 512, 0, stream>>>(x, out);
  }
}